// Round 5
// baseline (184.963 us; speedup 1.0000x reference)
//
#include <hip/hip_runtime.h>
#include <stdint.h>

#define BB 128
#define SS 4096
#define DD 64
#define HH 256

typedef short bf16x8 __attribute__((ext_vector_type(8)));
typedef float f32x16 __attribute__((ext_vector_type(16)));

__device__ __forceinline__ uint32_t cvt_pk_bf16(float lo, float hi) {
  uint32_t r;
  asm("v_cvt_pk_bf16_f32 %0, %1, %2" : "=v"(r) : "v"(lo), "v"(hi));
  return r;
}

// v_permlane32_swap_b32: new_a = [a.row0, b.row0], new_b = [a.row1, b.row1]
__device__ __forceinline__ void permswap(uint32_t& a, uint32_t& b) {
  asm("v_permlane32_swap_b32 %0, %1" : "+v"(a), "+v"(b));
}

__device__ __forceinline__ float silu_f(float v) {
  float e = __expf(-v);
  return v * __builtin_amdgcn_rcpf(1.0f + e);
}

// ---------------- pre-pass: transpose + f32->bf16 weights into workspace ----
// W1 f32 [B][64][256] -> W1t bf16 [B][256][64]  (GEMM1 A, K=d contiguous)
// W2 f32 [B][256][64] -> W2t bf16 [B][64][256]  (GEMM2 A, K=h contiguous)
__global__ __launch_bounds__(256) void transpose_w(
    const float* __restrict__ W1, const float* __restrict__ W2,
    ushort* __restrict__ W1t, ushort* __restrict__ W2t) {
  int g = blockIdx.x * 256 + threadIdx.x;
  const int half = (BB * DD * HH) / 8;  // 262144
  float v[8];
  if (g < half) {
    size_t e = (size_t)g * 8;              // W1t element, [b][h][d]
    int b = (int)(e >> 14);
    int rem = (int)(e & 16383);
    int h = rem >> 6;
    int d0 = rem & 63;
    const float* src = W1 + ((size_t)b << 14) + h;  // + d*256
#pragma unroll
    for (int j = 0; j < 8; ++j) v[j] = src[(size_t)(d0 + j) << 8];
    uint4 o;
    o.x = cvt_pk_bf16(v[0], v[1]); o.y = cvt_pk_bf16(v[2], v[3]);
    o.z = cvt_pk_bf16(v[4], v[5]); o.w = cvt_pk_bf16(v[6], v[7]);
    *reinterpret_cast<uint4*>(W1t + e) = o;
  } else if (g < 2 * half) {
    size_t e = (size_t)(g - half) * 8;     // W2t element, [b][d][h]
    int b = (int)(e >> 14);
    int rem = (int)(e & 16383);
    int d = rem >> 8;
    int h0 = rem & 255;
    const float* src = W2 + ((size_t)b << 14) + d;  // + h*64
#pragma unroll
    for (int j = 0; j < 8; ++j) v[j] = src[(size_t)(h0 + j) << 6];
    uint4 o;
    o.x = cvt_pk_bf16(v[0], v[1]); o.y = cvt_pk_bf16(v[2], v[3]);
    o.z = cvt_pk_bf16(v[4], v[5]); o.w = cvt_pk_bf16(v[6], v[7]);
    *reinterpret_cast<uint4*>(W2t + e) = o;
  }
}

// ---------------- main fused kernel ----------------
// Register-lean variant: each wave owns a 32-row s-tile of one b; H is
// processed in 8 chunks of 32 so only a 32x32 GEMM1 output (16 regs) is
// live at once. No LDS, no barriers. Weights read directly from global
// (bf16 pre-transposed, L2-resident per XCD). GEMM1->GEMM2 operand
// conversion fully in-register (cvt_pk + permlane32_swap).
__global__ __launch_bounds__(256, 3) void mlp_fused(
    const float* __restrict__ xg, const ushort* __restrict__ w1t,
    const ushort* __restrict__ w2t, float* __restrict__ outg) {
  const int tid = threadIdx.x;
  const int wave = tid >> 6;
  const int lane = tid & 63;
  const int l31 = lane & 31;
  const int g5 = lane >> 5;

  // 4096 blocks; XCD-aware swizzle: XCD k owns b in [16k, 16k+16)
  int raw = blockIdx.x;
  int logical = (raw & 7) * 512 + (raw >> 3);
  const int b = logical >> 5;            // 32 blocks per b
  const int st = logical & 31;
  const int s_base = st * 128 + wave * 32;

  const float* xb = xg + (((size_t)b * SS + s_base) << 6);
  const ushort* w1b = w1t + ((size_t)b << 14);
  const ushort* w2b = w2t + ((size_t)b << 14);

  // x B-frags for GEMM1 (f32 -> bf16): lane = x[s=l31][d=16kc+8g5..+7]
  bf16x8 bx[4];
#pragma unroll
  for (int kc = 0; kc < 4; ++kc) {
    const float* p = xb + ((size_t)l31 << 6) + kc * 16 + g5 * 8;
    float4 fa = *reinterpret_cast<const float4*>(p);
    float4 fb = *reinterpret_cast<const float4*>(p + 4);
    union { uint32_t u[4]; bf16x8 v; } cv;
    cv.u[0] = cvt_pk_bf16(fa.x, fa.y);
    cv.u[1] = cvt_pk_bf16(fa.z, fa.w);
    cv.u[2] = cvt_pk_bf16(fb.x, fb.y);
    cv.u[3] = cvt_pk_bf16(fb.z, fb.w);
    bx[kc] = cv.v;
  }

  // acc init = residual x (f32-exact) at output positions:
  // acc[mt][4q+j] = x[s=l31][d=32mt+8q+4g5+j]
  f32x16 acc[2];
  {
    const float* prow = xb + ((size_t)l31 << 6);
#pragma unroll
    for (int mt = 0; mt < 2; ++mt)
#pragma unroll
      for (int q = 0; q < 4; ++q) {
        float4 v =
            *reinterpret_cast<const float4*>(prow + mt * 32 + q * 8 + g5 * 4);
        acc[mt][4 * q + 0] = v.x;
        acc[mt][4 * q + 1] = v.y;
        acc[mt][4 * q + 2] = v.z;
        acc[mt][4 * q + 3] = v.w;
      }
  }

  const f32x16 vzero = {0.f, 0.f, 0.f, 0.f, 0.f, 0.f, 0.f, 0.f,
                        0.f, 0.f, 0.f, 0.f, 0.f, 0.f, 0.f, 0.f};

#pragma unroll
  for (int hc = 0; hc < 8; ++hc) {
    // ---- GEMM1 (swapped, 32h x 32s): A-frags from global (L2-hot) ----
    bf16x8 a1[4];
#pragma unroll
    for (int kc = 0; kc < 4; ++kc)
      a1[kc] = *reinterpret_cast<const bf16x8*>(
          w1b + ((size_t)(hc * 32 + l31) << 6) + kc * 16 + g5 * 8);
    f32x16 ah = vzero;
#pragma unroll
    for (int kc = 0; kc < 4; ++kc)
      ah = __builtin_amdgcn_mfma_f32_32x32x16_bf16(a1[kc], bx[kc], ah, 0, 0, 0);

    // ---- silu + pack + permlane32_swap -> GEMM2 B-frags (in-register) ----
    // ah idx=4q+j holds h_in_chunk = 8q+4g5+j (s = l31).
    // bh[c] word w: k_in_chunk = 16c + 8g5 + 2w + {0,1}.
    bf16x8 bh[2];
#pragma unroll
    for (int c = 0; c < 2; ++c) {
      uint32_t A0 = cvt_pk_bf16(silu_f(ah[8 * c + 0]), silu_f(ah[8 * c + 1]));
      uint32_t A1 = cvt_pk_bf16(silu_f(ah[8 * c + 2]), silu_f(ah[8 * c + 3]));
      uint32_t B0 = cvt_pk_bf16(silu_f(ah[8 * c + 4]), silu_f(ah[8 * c + 5]));
      uint32_t B1 = cvt_pk_bf16(silu_f(ah[8 * c + 6]), silu_f(ah[8 * c + 7]));
      permswap(A0, B0);
      permswap(A1, B1);
      union { uint32_t u[4]; bf16x8 v; } f;
      f.u[0] = A0; f.u[1] = A1; f.u[2] = B0; f.u[3] = B1;
      bh[c] = f.v;
    }

    // ---- GEMM2 (swapped): out^T += W2t[:, chunk] * h^T ----
    bf16x8 a2[2][2];
#pragma unroll
    for (int mt = 0; mt < 2; ++mt)
#pragma unroll
      for (int c = 0; c < 2; ++c)
        a2[mt][c] = *reinterpret_cast<const bf16x8*>(
            w2b + ((size_t)(mt * 32 + l31) << 8) + hc * 32 + c * 16 + g5 * 8);
#pragma unroll
    for (int c = 0; c < 2; ++c)
#pragma unroll
      for (int mt = 0; mt < 2; ++mt)
        acc[mt] = __builtin_amdgcn_mfma_f32_32x32x16_bf16(a2[mt][c], bh[c],
                                                          acc[mt], 0, 0, 0);
  }

  // ---- epilogue: direct global stores ----
  float* prow = outg + (((size_t)b * SS + s_base + l31) << 6);
#pragma unroll
  for (int mt = 0; mt < 2; ++mt)
#pragma unroll
    for (int q = 0; q < 4; ++q) {
      float4 v;
      v.x = acc[mt][4 * q + 0];
      v.y = acc[mt][4 * q + 1];
      v.z = acc[mt][4 * q + 2];
      v.w = acc[mt][4 * q + 3];
      *reinterpret_cast<float4*>(prow + mt * 32 + q * 8 + g5 * 4) = v;
    }
}

extern "C" void kernel_launch(void* const* d_in, const int* in_sizes, int n_in,
                              void* d_out, int out_size, void* d_ws, size_t ws_size,
                              hipStream_t stream) {
  const float* x  = (const float*)d_in[0];
  const float* W1 = (const float*)d_in[1];
  const float* W2 = (const float*)d_in[2];
  float* out = (float*)d_out;

  ushort* W1t = (ushort*)d_ws;                       // bf16 [B][256][64]
  ushort* W2t = W1t + (size_t)BB * DD * HH;          // bf16 [B][64][256]

  transpose_w<<<2048, 256, 0, stream>>>(W1, W2, W1t, W2t);
  mlp_fused<<<4096, 256, 0, stream>>>(x, W1t, W2t, out);
}

// Round 6
// 91.385 us; speedup vs baseline: 2.0240x; 2.0240x over previous
//
#include <hip/hip_runtime.h>
#include <stdint.h>

#define BB 128
#define SS 4096
#define DD 64
#define HH 256

typedef short bf16x8 __attribute__((ext_vector_type(8)));
typedef float f32x16 __attribute__((ext_vector_type(16)));

__device__ __forceinline__ uint32_t cvt_pk_bf16(float lo, float hi) {
  uint32_t r;
  asm("v_cvt_pk_bf16_f32 %0, %1, %2" : "=v"(r) : "v"(lo), "v"(hi));
  return r;
}

// v_permlane32_swap_b32: new_a = [a.row0, b.row0], new_b = [a.row1, b.row1]
__device__ __forceinline__ void permswap(uint32_t& a, uint32_t& b) {
  asm("v_permlane32_swap_b32 %0, %1" : "+v"(a), "+v"(b));
}

__device__ __forceinline__ float silu_f(float v) {
  float e = __expf(-v);
  return v * __builtin_amdgcn_rcpf(1.0f + e);
}

__device__ __forceinline__ void gload16(const void* g, void* l) {
  __builtin_amdgcn_global_load_lds(
      (const __attribute__((address_space(1))) void*)g,
      (__attribute__((address_space(3))) void*)l, 16, 0, 0);
}

// ---------------- pre-pass: transpose + f32->bf16 weights into workspace ----
// W1 f32 [B][64][256] -> W1t bf16 [B][256][64]  (GEMM1 A, K=d contiguous)
// W2 f32 [B][256][64] -> W2t bf16 [B][64][256]  (GEMM2 A, K=h contiguous)
__global__ __launch_bounds__(256) void transpose_w(
    const float* __restrict__ W1, const float* __restrict__ W2,
    ushort* __restrict__ W1t, ushort* __restrict__ W2t) {
  int g = blockIdx.x * 256 + threadIdx.x;
  const int half = (BB * DD * HH) / 8;  // 262144
  float v[8];
  if (g < half) {
    size_t e = (size_t)g * 8;              // W1t element, [b][h][d]
    int b = (int)(e >> 14);
    int rem = (int)(e & 16383);
    int h = rem >> 6;
    int d0 = rem & 63;
    const float* src = W1 + ((size_t)b << 14) + h;  // + d*256
#pragma unroll
    for (int j = 0; j < 8; ++j) v[j] = src[(size_t)(d0 + j) << 8];
    uint4 o;
    o.x = cvt_pk_bf16(v[0], v[1]); o.y = cvt_pk_bf16(v[2], v[3]);
    o.z = cvt_pk_bf16(v[4], v[5]); o.w = cvt_pk_bf16(v[6], v[7]);
    *reinterpret_cast<uint4*>(W1t + e) = o;
  } else if (g < 2 * half) {
    size_t e = (size_t)(g - half) * 8;     // W2t element, [b][d][h]
    int b = (int)(e >> 14);
    int rem = (int)(e & 16383);
    int d = rem >> 8;
    int h0 = rem & 255;
    const float* src = W2 + ((size_t)b << 14) + d;  // + h*64
#pragma unroll
    for (int j = 0; j < 8; ++j) v[j] = src[(size_t)(h0 + j) << 6];
    uint4 o;
    o.x = cvt_pk_bf16(v[0], v[1]); o.y = cvt_pk_bf16(v[2], v[3]);
    o.z = cvt_pk_bf16(v[4], v[5]); o.w = cvt_pk_bf16(v[6], v[7]);
    *reinterpret_cast<uint4*>(W2t + e) = o;
  }
}

// ---------------- main fused kernel ----------------
// Block = 512 thr (8 waves), covers one b's 256-row s-tile (wave = 32 rows).
// LDS 64 KB (weights only, shared by 8 waves; 2 blocks/CU):
//   [0,32K)   W1t[h][d] bf16, 128B rows, o ^= ((o>>7)&7)<<4   (a1: 4-way ok)
//   [32K,64K) W2t[d][h] bf16, 512B rows, o ^= ((o>>9)&31)<<4  (a2: conflict-free)
// h processed in 8 chunks of 32; GEMM1 output -> GEMM2 B-frags in-register
// (cvt_pk + permlane32_swap). One barrier total; direct f32 stores.
__global__ __launch_bounds__(512, 4) void mlp_fused(
    const float* __restrict__ xg, const ushort* __restrict__ w1t,
    const ushort* __restrict__ w2t, float* __restrict__ outg) {
  __shared__ int4 lds4[65536 / 16];
  char* lds = (char*)lds4;

  const int tid = threadIdx.x;
  const int wave = tid >> 6;
  const int lane = tid & 63;
  const int l31 = lane & 31;
  const int g5 = lane >> 5;

  // 2048 blocks; XCD-aware swizzle: XCD k owns b in [16k, 16k+16)
  int raw = blockIdx.x;
  int logical = (raw & 7) * 256 + (raw >> 3);
  const int b = logical >> 4;            // 16 blocks per b
  const int st = logical & 15;
  const int s_base = st * 256 + wave * 32;

  const float* xb = xg + (((size_t)b * SS + s_base) << 6);
  const ushort* w1b = w1t + ((size_t)b << 14);
  const ushort* w2b = w2t + ((size_t)b << 14);

  // stage weights: pre-swizzled global source, linear LDS dest (8 KB/round)
#pragma unroll
  for (int r = 0; r < 4; ++r) {
    uint32_t o = (uint32_t)(r * 8192 + tid * 16);
    gload16((const char*)w1b + (o ^ (((o >> 7) & 7) << 4)), lds + o);
    gload16((const char*)w2b + (o ^ (((o >> 9) & 31) << 4)), lds + 32768 + o);
  }

  // x B-frags for GEMM1 (f32 -> bf16): lane = x[s=l31][d=16kc+8g5..+7]
  bf16x8 bx[4];
#pragma unroll
  for (int kc = 0; kc < 4; ++kc) {
    const float* p = xb + ((size_t)l31 << 6) + kc * 16 + g5 * 8;
    float4 fa = *reinterpret_cast<const float4*>(p);
    float4 fb = *reinterpret_cast<const float4*>(p + 4);
    union { uint32_t u[4]; bf16x8 v; } cv;
    cv.u[0] = cvt_pk_bf16(fa.x, fa.y);
    cv.u[1] = cvt_pk_bf16(fa.z, fa.w);
    cv.u[2] = cvt_pk_bf16(fb.x, fb.y);
    cv.u[3] = cvt_pk_bf16(fb.z, fb.w);
    bx[kc] = cv.v;
  }

  // acc init = residual x (f32-exact): acc[mt][4q+j] = x[s=l31][d=32mt+8q+4g5+j]
  f32x16 acc[2];
  {
    const float* prow = xb + ((size_t)l31 << 6);
#pragma unroll
    for (int mt = 0; mt < 2; ++mt)
#pragma unroll
      for (int q = 0; q < 4; ++q) {
        float4 v =
            *reinterpret_cast<const float4*>(prow + mt * 32 + q * 8 + g5 * 4);
        acc[mt][4 * q + 0] = v.x;
        acc[mt][4 * q + 1] = v.y;
        acc[mt][4 * q + 2] = v.z;
        acc[mt][4 * q + 3] = v.w;
      }
  }

  __syncthreads();  // weight staging complete

  const f32x16 vzero = {0.f, 0.f, 0.f, 0.f, 0.f, 0.f, 0.f, 0.f,
                        0.f, 0.f, 0.f, 0.f, 0.f, 0.f, 0.f, 0.f};

#pragma unroll
  for (int hc = 0; hc < 8; ++hc) {
    // ---- GEMM1 (swapped, 32h x 32s): a1 from LDS ----
    bf16x8 a1[4];
#pragma unroll
    for (int kc = 0; kc < 4; ++kc) {
      uint32_t o = (uint32_t)((hc * 32 + l31) * 128 + kc * 32 + g5 * 16);
      o ^= ((o >> 7) & 7) << 4;
      a1[kc] = *reinterpret_cast<const bf16x8*>(lds + o);
    }
    f32x16 ah = vzero;
#pragma unroll
    for (int kc = 0; kc < 4; ++kc)
      ah = __builtin_amdgcn_mfma_f32_32x32x16_bf16(a1[kc], bx[kc], ah, 0, 0, 0);

    // ---- silu + pack + permlane32_swap -> GEMM2 B-frags (in-register) ----
    // ah idx=4q+j holds h_in_chunk = 8q+4g5+j (s = l31).
    // bh[c] word w: k_in_chunk = 16c + 8g5 + 2w + {0,1}.
    bf16x8 bh[2];
#pragma unroll
    for (int c = 0; c < 2; ++c) {
      uint32_t A0 = cvt_pk_bf16(silu_f(ah[8 * c + 0]), silu_f(ah[8 * c + 1]));
      uint32_t A1 = cvt_pk_bf16(silu_f(ah[8 * c + 2]), silu_f(ah[8 * c + 3]));
      uint32_t B0 = cvt_pk_bf16(silu_f(ah[8 * c + 4]), silu_f(ah[8 * c + 5]));
      uint32_t B1 = cvt_pk_bf16(silu_f(ah[8 * c + 6]), silu_f(ah[8 * c + 7]));
      permswap(A0, B0);
      permswap(A1, B1);
      union { uint32_t u[4]; bf16x8 v; } f;
      f.u[0] = A0; f.u[1] = A1; f.u[2] = B0; f.u[3] = B1;
      bh[c] = f.v;
    }

    // ---- GEMM2 (swapped): out^T += W2t[:, chunk] * h^T, a2 from LDS ----
    bf16x8 a2[2][2];
#pragma unroll
    for (int mt = 0; mt < 2; ++mt)
#pragma unroll
      for (int c = 0; c < 2; ++c) {
        uint32_t o = (uint32_t)((mt * 32 + l31) * 512 + hc * 64 + c * 32 + g5 * 16);
        o ^= ((o >> 9) & 31) << 4;
        a2[mt][c] = *reinterpret_cast<const bf16x8*>(lds + 32768 + o);
      }
#pragma unroll
    for (int c = 0; c < 2; ++c)
#pragma unroll
      for (int mt = 0; mt < 2; ++mt)
        acc[mt] = __builtin_amdgcn_mfma_f32_32x32x16_bf16(a2[mt][c], bh[c],
                                                          acc[mt], 0, 0, 0);
  }

  // ---- epilogue: direct global stores (WRITE_SIZE stays ideal per r4/r5) ----
  float* prow = outg + (((size_t)b * SS + s_base + l31) << 6);
#pragma unroll
  for (int mt = 0; mt < 2; ++mt)
#pragma unroll
    for (int q = 0; q < 4; ++q) {
      float4 v;
      v.x = acc[mt][4 * q + 0];
      v.y = acc[mt][4 * q + 1];
      v.z = acc[mt][4 * q + 2];
      v.w = acc[mt][4 * q + 3];
      *reinterpret_cast<float4*>(prow + mt * 32 + q * 8 + g5 * 4) = v;
    }
}

extern "C" void kernel_launch(void* const* d_in, const int* in_sizes, int n_in,
                              void* d_out, int out_size, void* d_ws, size_t ws_size,
                              hipStream_t stream) {
  const float* x  = (const float*)d_in[0];
  const float* W1 = (const float*)d_in[1];
  const float* W2 = (const float*)d_in[2];
  float* out = (float*)d_out;

  ushort* W1t = (ushort*)d_ws;                       // bf16 [B][256][64]
  ushort* W2t = W1t + (size_t)BB * DD * HH;          // bf16 [B][64][256]

  transpose_w<<<2048, 256, 0, stream>>>(W1, W2, W1t, W2t);
  mlp_fused<<<2048, 512, 0, stream>>>(x, W1t, W2t, out);
}

// Round 7
// 86.928 us; speedup vs baseline: 2.1278x; 1.0513x over previous
//
#include <hip/hip_runtime.h>
#include <stdint.h>

#define BB 128
#define SS 4096
#define DD 64
#define HH 256

typedef short bf16x8 __attribute__((ext_vector_type(8)));
typedef float f32x16 __attribute__((ext_vector_type(16)));

__device__ __forceinline__ uint32_t cvt_pk_bf16(float lo, float hi) {
  uint32_t r;
  asm("v_cvt_pk_bf16_f32 %0, %1, %2" : "=v"(r) : "v"(lo), "v"(hi));
  return r;
}

// v_permlane32_swap_b32: new_a = [a.row0, b.row0], new_b = [a.row1, b.row1]
__device__ __forceinline__ void permswap(uint32_t& a, uint32_t& b) {
  asm("v_permlane32_swap_b32 %0, %1" : "+v"(a), "+v"(b));
}

__device__ __forceinline__ float silu_f(float v) {
  float e = __expf(-v);
  return v * __builtin_amdgcn_rcpf(1.0f + e);
}

__device__ __forceinline__ void gload16(const void* g, void* l) {
  __builtin_amdgcn_global_load_lds(
      (const __attribute__((address_space(1))) void*)g,
      (__attribute__((address_space(3))) void*)l, 16, 0, 0);
}

// -------- pre-pass: weights -> FRAGMENT-MAJOR bf16 layout in workspace -----
// Every wave consumes identical MFMA A-fragments, so store them pre-shaped:
// W1f: per b, 32 tiles (hc*4+kc) of 64 lanes x 16B:
//   lane holds W1[d = kc*16+(lane>>5)*8 + j][h = hc*32+(lane&31)], j=0..7
// W2f: per b, 32 tiles (hc*4+mt*2+c) of 64 lanes x 16B:
//   lane holds W2[h = hc*32+c*16+(lane>>5)*8 + j][d = mt*32+(lane&31)]
__global__ __launch_bounds__(256) void transpose_w(
    const float* __restrict__ W1, const float* __restrict__ W2,
    ushort* __restrict__ W1f, ushort* __restrict__ W2f) {
  int g = blockIdx.x * 256 + threadIdx.x;
  const int half = (BB * DD * HH) / 8;  // 262144
  float v[8];
  if (g < half) {
    size_t e = (size_t)g * 8;            // ushort index: b|tile|lane|j
    int b = (int)(e >> 14);
    int rem = (int)(e & 16383);
    int tile = rem >> 9;                 // hc*4 + kc
    int lane6 = (rem >> 3) & 63;
    int hc = tile >> 2, kc = tile & 3;
    int h = hc * 32 + (lane6 & 31);
    int d0 = kc * 16 + (lane6 >> 5) * 8;
    const float* src = W1 + ((size_t)b << 14) + h;  // + d*256
#pragma unroll
    for (int j = 0; j < 8; ++j) v[j] = src[(size_t)(d0 + j) << 8];
    uint4 o;
    o.x = cvt_pk_bf16(v[0], v[1]); o.y = cvt_pk_bf16(v[2], v[3]);
    o.z = cvt_pk_bf16(v[4], v[5]); o.w = cvt_pk_bf16(v[6], v[7]);
    *reinterpret_cast<uint4*>(W1f + e) = o;
  } else if (g < 2 * half) {
    size_t e = (size_t)(g - half) * 8;
    int b = (int)(e >> 14);
    int rem = (int)(e & 16383);
    int tile = rem >> 9;                 // hc*4 + mt*2 + c
    int lane6 = (rem >> 3) & 63;
    int hc = tile >> 2, mt = (tile >> 1) & 1, c = tile & 1;
    int d = mt * 32 + (lane6 & 31);
    int h0 = hc * 32 + c * 16 + (lane6 >> 5) * 8;
    const float* src = W2 + ((size_t)b << 14) + d;  // + h*64
#pragma unroll
    for (int j = 0; j < 8; ++j) v[j] = src[(size_t)(h0 + j) << 6];
    uint4 o;
    o.x = cvt_pk_bf16(v[0], v[1]); o.y = cvt_pk_bf16(v[2], v[3]);
    o.z = cvt_pk_bf16(v[4], v[5]); o.w = cvt_pk_bf16(v[6], v[7]);
    *reinterpret_cast<uint4*>(W2f + e) = o;
  }
}

// ---------------- main fused kernel ----------------
// Block = 512 thr (8 waves), one b, 256 s-rows (wave = 32 rows).
// LDS 64 KB fragment-major: W1f tiles [0,32K), W2f tiles [32K,64K).
// All LDS reads are ds_read_b128 at (lane*16 + literal offset): zero address
// math, zero bank conflicts. h in 8 chunks of 32; GEMM1(hc+1) is interleaved
// with silu(hc) (independent MFMA vs trans-pipe work); GEMM1->GEMM2 operand
// conversion in-register (cvt_pk + permlane32_swap). One barrier total.
__global__ __launch_bounds__(512, 4) void mlp_fused(
    const float* __restrict__ xg, const ushort* __restrict__ w1f,
    const ushort* __restrict__ w2f, float* __restrict__ outg) {
  __shared__ int4 lds4[65536 / 16];
  char* lds = (char*)lds4;

  const int tid = threadIdx.x;
  const int wave = tid >> 6;
  const int lane = tid & 63;
  const int l31 = lane & 31;
  const int g5 = lane >> 5;

  // 2048 blocks; XCD-aware swizzle: XCD k owns b in [16k, 16k+16)
  int raw = blockIdx.x;
  int logical = (raw & 7) * 256 + (raw >> 3);
  const int b = logical >> 4;            // 16 blocks per b
  const int st = logical & 15;
  const int s_base = st * 256 + wave * 32;

  const float* xb = xg + (((size_t)b * SS + s_base) << 6);
  const char* w1b = (const char*)(w1f + ((size_t)b << 14));
  const char* w2b = (const char*)(w2f + ((size_t)b << 14));

  // stage weights: pure linear copy (fragment-major already)
#pragma unroll
  for (int r = 0; r < 4; ++r) {
    uint32_t o = (uint32_t)(r * 8192 + tid * 16);
    gload16(w1b + o, lds + o);
    gload16(w2b + o, lds + 32768 + o);
  }

  // x B-frags for GEMM1 (f32 -> bf16): lane = x[s=l31][d=16kc+8g5..+7]
  bf16x8 bx[4];
#pragma unroll
  for (int kc = 0; kc < 4; ++kc) {
    const float* p = xb + ((size_t)l31 << 6) + kc * 16 + g5 * 8;
    float4 fa = *reinterpret_cast<const float4*>(p);
    float4 fb = *reinterpret_cast<const float4*>(p + 4);
    union { uint32_t u[4]; bf16x8 v; } cv;
    cv.u[0] = cvt_pk_bf16(fa.x, fa.y);
    cv.u[1] = cvt_pk_bf16(fa.z, fa.w);
    cv.u[2] = cvt_pk_bf16(fb.x, fb.y);
    cv.u[3] = cvt_pk_bf16(fb.z, fb.w);
    bx[kc] = cv.v;
  }

  // acc init = residual x (f32-exact): acc[mt][4q+j] = x[s=l31][d=32mt+8q+4g5+j]
  f32x16 acc[2];
  {
    const float* prow = xb + ((size_t)l31 << 6);
#pragma unroll
    for (int mt = 0; mt < 2; ++mt)
#pragma unroll
      for (int q = 0; q < 4; ++q) {
        float4 v =
            *reinterpret_cast<const float4*>(prow + mt * 32 + q * 8 + g5 * 4);
        acc[mt][4 * q + 0] = v.x;
        acc[mt][4 * q + 1] = v.y;
        acc[mt][4 * q + 2] = v.z;
        acc[mt][4 * q + 3] = v.w;
      }
  }

  __syncthreads();  // weight staging complete

  const char* lw1 = lds + lane * 16;
  const char* lw2 = lds + 32768 + lane * 16;

  const f32x16 vzero = {0.f, 0.f, 0.f, 0.f, 0.f, 0.f, 0.f, 0.f,
                        0.f, 0.f, 0.f, 0.f, 0.f, 0.f, 0.f, 0.f};

  // prologue: GEMM1 chunk 0
  f32x16 ah_cur = vzero;
#pragma unroll
  for (int kc = 0; kc < 4; ++kc) {
    bf16x8 a1 = *reinterpret_cast<const bf16x8*>(lw1 + kc * 1024);
    ah_cur = __builtin_amdgcn_mfma_f32_32x32x16_bf16(a1, bx[kc], ah_cur, 0, 0, 0);
  }

#pragma unroll
  for (int hc = 0; hc < 8; ++hc) {
    // ---- silu + pack + permlane32_swap -> GEMM2 B-frags (trans/VALU) ----
    // ah idx=4q+j holds h_in_chunk = 8q+4g5+j (s = l31).
    // bh[c] word w: k_in_chunk = 16c + 8g5 + 2w + {0,1}.
    bf16x8 bh[2];
#pragma unroll
    for (int c = 0; c < 2; ++c) {
      uint32_t A0 = cvt_pk_bf16(silu_f(ah_cur[8 * c + 0]), silu_f(ah_cur[8 * c + 1]));
      uint32_t A1 = cvt_pk_bf16(silu_f(ah_cur[8 * c + 2]), silu_f(ah_cur[8 * c + 3]));
      uint32_t B0 = cvt_pk_bf16(silu_f(ah_cur[8 * c + 4]), silu_f(ah_cur[8 * c + 5]));
      uint32_t B1 = cvt_pk_bf16(silu_f(ah_cur[8 * c + 6]), silu_f(ah_cur[8 * c + 7]));
      permswap(A0, B0);
      permswap(A1, B1);
      union { uint32_t u[4]; bf16x8 v; } f;
      f.u[0] = A0; f.u[1] = A1; f.u[2] = B0; f.u[3] = B1;
      bh[c] = f.v;
    }

    // ---- GEMM1 for next chunk (independent MFMA, overlaps silu above) ----
    f32x16 ah_nxt = vzero;
    if (hc < 7) {
#pragma unroll
      for (int kc = 0; kc < 4; ++kc) {
        bf16x8 a1 = *reinterpret_cast<const bf16x8*>(
            lw1 + ((hc + 1) * 4 + kc) * 1024);
        ah_nxt =
            __builtin_amdgcn_mfma_f32_32x32x16_bf16(a1, bx[kc], ah_nxt, 0, 0, 0);
      }
    }

    // ---- GEMM2 (swapped): out^T += W2f[:, chunk] * h^T ----
#pragma unroll
    for (int c = 0; c < 2; ++c)
#pragma unroll
      for (int mt = 0; mt < 2; ++mt) {
        bf16x8 a2 = *reinterpret_cast<const bf16x8*>(
            lw2 + (hc * 4 + mt * 2 + c) * 1024);
        acc[mt] =
            __builtin_amdgcn_mfma_f32_32x32x16_bf16(a2, bh[c], acc[mt], 0, 0, 0);
      }

    ah_cur = ah_nxt;
  }

  // ---- epilogue: direct global stores ----
  float* prow = outg + (((size_t)b * SS + s_base + l31) << 6);
#pragma unroll
  for (int mt = 0; mt < 2; ++mt)
#pragma unroll
    for (int q = 0; q < 4; ++q) {
      float4 v;
      v.x = acc[mt][4 * q + 0];
      v.y = acc[mt][4 * q + 1];
      v.z = acc[mt][4 * q + 2];
      v.w = acc[mt][4 * q + 3];
      *reinterpret_cast<float4*>(prow + mt * 32 + q * 8 + g5 * 4) = v;
    }
}

extern "C" void kernel_launch(void* const* d_in, const int* in_sizes, int n_in,
                              void* d_out, int out_size, void* d_ws, size_t ws_size,
                              hipStream_t stream) {
  const float* x  = (const float*)d_in[0];
  const float* W1 = (const float*)d_in[1];
  const float* W2 = (const float*)d_in[2];
  float* out = (float*)d_out;

  ushort* W1f = (ushort*)d_ws;                       // bf16 frag-major, 4 MB
  ushort* W2f = W1f + (size_t)BB * DD * HH;          // bf16 frag-major, 4 MB

  transpose_w<<<2048, 256, 0, stream>>>(W1, W2, W1f, W2f);
  mlp_fused<<<2048, 512, 0, stream>>>(x, W1f, W2f, out);
}

// Round 8
// 85.079 us; speedup vs baseline: 2.1740x; 1.0217x over previous
//
#include <hip/hip_runtime.h>
#include <stdint.h>

#define BB 128
#define SS 4096
#define DD 64
#define HH 256

typedef short bf16x8 __attribute__((ext_vector_type(8)));
typedef float f32x16 __attribute__((ext_vector_type(16)));

__device__ __forceinline__ uint32_t cvt_pk_bf16(float lo, float hi) {
  uint32_t r;
  asm("v_cvt_pk_bf16_f32 %0, %1, %2" : "=v"(r) : "v"(lo), "v"(hi));
  return r;
}

// v_permlane32_swap_b32: new_a = [a.row0, b.row0], new_b = [a.row1, b.row1]
__device__ __forceinline__ void permswap(uint32_t& a, uint32_t& b) {
  asm("v_permlane32_swap_b32 %0, %1" : "+v"(a), "+v"(b));
}

__device__ __forceinline__ float silu_f(float v) {
  float e = __expf(-v);
  return v * __builtin_amdgcn_rcpf(1.0f + e);
}

__device__ __forceinline__ void gload16(const void* g, void* l) {
  __builtin_amdgcn_global_load_lds(
      (const __attribute__((address_space(1))) void*)g,
      (__attribute__((address_space(3))) void*)l, 16, 0, 0);
}

// -------- pre-pass: weights -> FRAGMENT-MAJOR bf16 layout in workspace -----
// W1f: per b, 32 tiles (hc*4+kc) of 64 lanes x 16B:
//   lane holds W1[d = kc*16+(lane>>5)*8 + j][h = hc*32+(lane&31)], j=0..7
// W2f: per b, 32 tiles (hc*4+mt*2+c) of 64 lanes x 16B:
//   lane holds W2[h = hc*32+c*16+(lane>>5)*8 + j][d = mt*32+(lane&31)]
__global__ __launch_bounds__(256) void transpose_w(
    const float* __restrict__ W1, const float* __restrict__ W2,
    ushort* __restrict__ W1f, ushort* __restrict__ W2f) {
  int g = blockIdx.x * 256 + threadIdx.x;
  const int half = (BB * DD * HH) / 8;  // 262144
  float v[8];
  if (g < half) {
    size_t e = (size_t)g * 8;            // ushort index: b|tile|lane|j
    int b = (int)(e >> 14);
    int rem = (int)(e & 16383);
    int tile = rem >> 9;                 // hc*4 + kc
    int lane6 = (rem >> 3) & 63;
    int hc = tile >> 2, kc = tile & 3;
    int h = hc * 32 + (lane6 & 31);
    int d0 = kc * 16 + (lane6 >> 5) * 8;
    const float* src = W1 + ((size_t)b << 14) + h;  // + d*256
#pragma unroll
    for (int j = 0; j < 8; ++j) v[j] = src[(size_t)(d0 + j) << 8];
    uint4 o;
    o.x = cvt_pk_bf16(v[0], v[1]); o.y = cvt_pk_bf16(v[2], v[3]);
    o.z = cvt_pk_bf16(v[4], v[5]); o.w = cvt_pk_bf16(v[6], v[7]);
    *reinterpret_cast<uint4*>(W1f + e) = o;
  } else if (g < 2 * half) {
    size_t e = (size_t)(g - half) * 8;
    int b = (int)(e >> 14);
    int rem = (int)(e & 16383);
    int tile = rem >> 9;                 // hc*4 + mt*2 + c
    int lane6 = (rem >> 3) & 63;
    int hc = tile >> 2, mt = (tile >> 1) & 1, c = tile & 1;
    int d = mt * 32 + (lane6 & 31);
    int h0 = hc * 32 + c * 16 + (lane6 >> 5) * 8;
    const float* src = W2 + ((size_t)b << 14) + d;  // + h*64
#pragma unroll
    for (int j = 0; j < 8; ++j) v[j] = src[(size_t)(h0 + j) << 6];
    uint4 o;
    o.x = cvt_pk_bf16(v[0], v[1]); o.y = cvt_pk_bf16(v[2], v[3]);
    o.z = cvt_pk_bf16(v[4], v[5]); o.w = cvt_pk_bf16(v[6], v[7]);
    *reinterpret_cast<uint4*>(W2f + e) = o;
  }
}

// ---------------- main fused kernel ----------------
// Block = 512 thr (8 waves), one b, 256 s-rows (wave = 32 rows).
// LDS 64 KB fragment-major: W1f tiles [0,32K), W2f tiles [32K,64K).
// All LDS reads are ds_read_b128 at (lane*16 + literal offset): zero address
// math, zero bank conflicts. h in 8 chunks of 32. Register-lean (no manual
// software pipeline): rely on 5 waves/SIMD TLP to hide MFMA/trans latency.
// GEMM1->GEMM2 operand conversion in-register (cvt_pk + permlane32_swap).
__global__ __launch_bounds__(512, 5) void mlp_fused(
    const float* __restrict__ xg, const ushort* __restrict__ w1f,
    const ushort* __restrict__ w2f, float* __restrict__ outg) {
  __shared__ int4 lds4[65536 / 16];
  char* lds = (char*)lds4;

  const int tid = threadIdx.x;
  const int wave = tid >> 6;
  const int lane = tid & 63;
  const int l31 = lane & 31;
  const int g5 = lane >> 5;

  // 2048 blocks; XCD-aware swizzle: XCD k owns b in [16k, 16k+16)
  int raw = blockIdx.x;
  int logical = (raw & 7) * 256 + (raw >> 3);
  const int b = logical >> 4;            // 16 blocks per b
  const int st = logical & 15;
  const int s_base = st * 256 + wave * 32;

  const float* xb = xg + (((size_t)b * SS + s_base) << 6);
  const char* w1b = (const char*)(w1f + ((size_t)b << 14));
  const char* w2b = (const char*)(w2f + ((size_t)b << 14));

  // stage weights: pure linear copy (fragment-major already)
#pragma unroll
  for (int r = 0; r < 4; ++r) {
    uint32_t o = (uint32_t)(r * 8192 + tid * 16);
    gload16(w1b + o, lds + o);
    gload16(w2b + o, lds + 32768 + o);
  }

  // x B-frags for GEMM1 (f32 -> bf16): lane = x[s=l31][d=16kc+8g5..+7]
  bf16x8 bx[4];
#pragma unroll
  for (int kc = 0; kc < 4; ++kc) {
    const float* p = xb + ((size_t)l31 << 6) + kc * 16 + g5 * 8;
    float4 fa = *reinterpret_cast<const float4*>(p);
    float4 fb = *reinterpret_cast<const float4*>(p + 4);
    union { uint32_t u[4]; bf16x8 v; } cv;
    cv.u[0] = cvt_pk_bf16(fa.x, fa.y);
    cv.u[1] = cvt_pk_bf16(fa.z, fa.w);
    cv.u[2] = cvt_pk_bf16(fb.x, fb.y);
    cv.u[3] = cvt_pk_bf16(fb.z, fb.w);
    bx[kc] = cv.v;
  }

  // acc init = residual x (f32-exact): acc[mt][4q+j] = x[s=l31][d=32mt+8q+4g5+j]
  f32x16 acc[2];
  {
    const float* prow = xb + ((size_t)l31 << 6);
#pragma unroll
    for (int mt = 0; mt < 2; ++mt)
#pragma unroll
      for (int q = 0; q < 4; ++q) {
        float4 v =
            *reinterpret_cast<const float4*>(prow + mt * 32 + q * 8 + g5 * 4);
        acc[mt][4 * q + 0] = v.x;
        acc[mt][4 * q + 1] = v.y;
        acc[mt][4 * q + 2] = v.z;
        acc[mt][4 * q + 3] = v.w;
      }
  }

  __syncthreads();  // weight staging complete

  const char* lw1 = lds + lane * 16;
  const char* lw2 = lds + 32768 + lane * 16;

  const f32x16 vzero = {0.f, 0.f, 0.f, 0.f, 0.f, 0.f, 0.f, 0.f,
                        0.f, 0.f, 0.f, 0.f, 0.f, 0.f, 0.f, 0.f};

#pragma unroll
  for (int hc = 0; hc < 8; ++hc) {
    // ---- GEMM1 (swapped, 32h x 32s): a1 from LDS, literal offsets ----
    f32x16 ah = vzero;
#pragma unroll
    for (int kc = 0; kc < 4; ++kc) {
      bf16x8 a1 = *reinterpret_cast<const bf16x8*>(lw1 + (hc * 4 + kc) * 1024);
      ah = __builtin_amdgcn_mfma_f32_32x32x16_bf16(a1, bx[kc], ah, 0, 0, 0);
    }

    // ---- silu + pack + permlane32_swap -> GEMM2 B-frags (in-register) ----
    // ah idx=4q+j holds h_in_chunk = 8q+4g5+j (s = l31).
    // bh[c] word w: k_in_chunk = 16c + 8g5 + 2w + {0,1}.
    bf16x8 bh[2];
#pragma unroll
    for (int c = 0; c < 2; ++c) {
      uint32_t A0 = cvt_pk_bf16(silu_f(ah[8 * c + 0]), silu_f(ah[8 * c + 1]));
      uint32_t A1 = cvt_pk_bf16(silu_f(ah[8 * c + 2]), silu_f(ah[8 * c + 3]));
      uint32_t B0 = cvt_pk_bf16(silu_f(ah[8 * c + 4]), silu_f(ah[8 * c + 5]));
      uint32_t B1 = cvt_pk_bf16(silu_f(ah[8 * c + 6]), silu_f(ah[8 * c + 7]));
      permswap(A0, B0);
      permswap(A1, B1);
      union { uint32_t u[4]; bf16x8 v; } f;
      f.u[0] = A0; f.u[1] = A1; f.u[2] = B0; f.u[3] = B1;
      bh[c] = f.v;
    }

    // ---- GEMM2 (swapped): out^T += W2f[:, chunk] * h^T ----
#pragma unroll
    for (int c = 0; c < 2; ++c)
#pragma unroll
      for (int mt = 0; mt < 2; ++mt) {
        bf16x8 a2 = *reinterpret_cast<const bf16x8*>(
            lw2 + (hc * 4 + mt * 2 + c) * 1024);
        acc[mt] =
            __builtin_amdgcn_mfma_f32_32x32x16_bf16(a2, bh[c], acc[mt], 0, 0, 0);
      }
  }

  // ---- epilogue: direct global stores ----
  float* prow = outg + (((size_t)b * SS + s_base + l31) << 6);
#pragma unroll
  for (int mt = 0; mt < 2; ++mt)
#pragma unroll
    for (int q = 0; q < 4; ++q) {
      float4 v;
      v.x = acc[mt][4 * q + 0];
      v.y = acc[mt][4 * q + 1];
      v.z = acc[mt][4 * q + 2];
      v.w = acc[mt][4 * q + 3];
      *reinterpret_cast<float4*>(prow + mt * 32 + q * 8 + g5 * 4) = v;
    }
}

extern "C" void kernel_launch(void* const* d_in, const int* in_sizes, int n_in,
                              void* d_out, int out_size, void* d_ws, size_t ws_size,
                              hipStream_t stream) {
  const float* x  = (const float*)d_in[0];
  const float* W1 = (const float*)d_in[1];
  const float* W2 = (const float*)d_in[2];
  float* out = (float*)d_out;

  ushort* W1f = (ushort*)d_ws;                       // bf16 frag-major, 4 MB
  ushort* W2f = W1f + (size_t)BB * DD * HH;          // bf16 frag-major, 4 MB

  transpose_w<<<2048, 256, 0, stream>>>(W1, W2, W1f, W2f);
  mlp_fused<<<2048, 512, 0, stream>>>(x, W1f, W2f, out);
}